// Round 9
// baseline (777.484 us; speedup 1.0000x reference)
//
#include <hip/hip_runtime.h>
#include <hip/hip_bf16.h>

#define HIDC 2048
#define NHEADS 16
#define HDIM 128
#define NB 4
#define NS 4096
#define NROWS (NB*NS)
#define QSTR 6144
#define EPSV 1e-6f

typedef __attribute__((ext_vector_type(8))) short s16x8;
typedef __attribute__((ext_vector_type(4))) float f32x4;
typedef __attribute__((ext_vector_type(8))) unsigned short u16x8;

static __device__ __forceinline__ unsigned short f2b(float f) {
  unsigned int u = __float_as_uint(f);
  u += 0x7fffu + ((u >> 16) & 1u);
  return (unsigned short)(u >> 16);
}
static __device__ __forceinline__ float b2f(unsigned short h) {
  return __uint_as_float(((unsigned int)h) << 16);
}

static __device__ __forceinline__ void gload_lds16(const unsigned short* g, unsigned short* l) {
  __builtin_amdgcn_global_load_lds(
      (const __attribute__((address_space(1))) void*)g,
      (__attribute__((address_space(3))) void*)l, 16, 0, 0);
}

// fp32 -> bf16 conversion for hs (16384 blocks) + 4 weights (2048 blocks each)
__global__ __launch_bounds__(256) void convert_all(
    const float* __restrict__ hs, const float* __restrict__ qw,
    const float* __restrict__ kw, const float* __restrict__ vw,
    const float* __restrict__ ow,
    unsigned short* __restrict__ hsb, unsigned short* __restrict__ qwb,
    unsigned short* __restrict__ kwb, unsigned short* __restrict__ vwb,
    unsigned short* __restrict__ owb)
{
  int bid = blockIdx.x;
  const float* src; unsigned short* dst; size_t base;
  if (bid < 16384) { src = hs; dst = hsb; base = (size_t)bid << 11; }
  else {
    int t = bid - 16384; int wsel = t >> 11; int wb = t & 2047;
    src = wsel == 0 ? qw : wsel == 1 ? kw : wsel == 2 ? vw : ow;
    dst = wsel == 0 ? qwb : wsel == 1 ? kwb : wsel == 2 ? vwb : owb;
    base = (size_t)wb << 11;
  }
  size_t i = base + ((size_t)threadIdx.x << 3);
  float4 a = *(const float4*)(src + i);
  float4 b = *(const float4*)(src + i + 4);
  u16x8 o;
  o[0] = f2b(a.x); o[1] = f2b(a.y); o[2] = f2b(a.z); o[3] = f2b(a.w);
  o[4] = f2b(b.x); o[5] = f2b(b.y); o[6] = f2b(b.z); o[7] = f2b(b.w);
  *(u16x8*)(dst + i) = o;
}

// 256x256-tile bf16 GEMM, 8 waves (2Mx4N), BK=32, ring-of-4 LDS slots,
// 3-deep vmem prefetch, SINGLE-EPOCH steps (1 barrier, 1 gate, no phases):
//   step s: vmcnt(4) | bar | read b0-3(slot s) + a0-7(slot s+1 -> set P^1) |
//           stage A,B(slot s+3) | sched_bar | 32 MFMA (a set P x b)
// The 12-read LDS drain overlaps the 1242-cyc MFMA epoch (reads consumed next
// step / late this step); only b0's arrival gates MFMA entry (~100 cyc).
// Safety: gate vmcnt(4) => slot s+1 resident before its a-reads; WAR on slot
// s-1 (= s+3 mod 4) barrier-ordered (b-reads of s-1 drained pre-MFMA pre-bar).
// XOR-swizzled LDS (0 conflicts). K fixed = 2048 (64 steps).
template<int QKV, int OUT_BF16>
__global__ __launch_bounds__(512, 2) void gemm256(
    const unsigned short* __restrict__ A,
    const unsigned short* __restrict__ B0,
    const unsigned short* __restrict__ B1,
    const unsigned short* __restrict__ B2,
    const float* __restrict__ bias0,
    const float* __restrict__ bias1,
    const float* __restrict__ bias2,
    void* __restrict__ Cp,
    int ntile, int astr, int ostr)
{
  __shared__ unsigned short lds[65536];   // 128 KiB: [slot:4][op:2][8192]
  const int tid = threadIdx.x;
  const int lane = tid & 63, wid = tid >> 6;
  const int wr = wid >> 2, wc = wid & 3;
  const int l15 = lane & 15, l4 = lane >> 4;

  // bijective XCD swizzle (grid % 8 == 0) + L2 chunking: 4 bm x all bn
  const int cpx = (int)gridDim.x >> 3;
  const int bidx = (int)blockIdx.x;
  const int wg = (bidx & 7) * cpx + (bidx >> 3);
  const int csz = ntile << 2;
  const int chunk = wg / csz;
  const int t = wg % csz;
  const int bm = ((chunk << 2) + (t & 3)) << 8;
  const int bn = (t >> 2) << 8;

  const unsigned short* Bp = B0;
  const float* bias = bias0;
  bool act = false;
  int bnw = bn;
  if (QKV) {
    int seg = bn >> 11;
    Bp = seg == 0 ? B0 : (seg == 1 ? B1 : B2);
    bias = seg == 0 ? bias0 : (seg == 1 ? bias1 : bias2);
    act = seg < 2;
    bnw = bn & 2047;
  }

  // staging: wave stages chunks {2*wid, 2*wid+1} of A and B. chunk = 16 rows
  // x 32 cols (1024B). source col inverse-swizzled (linear LDS write +
  // swizzled read = consistent involution).
  const int c0 = wid << 1;
  const int srow = lane >> 2;
  const int scol = (((lane & 3) ^ ((srow >> 1) & 3)) << 3);
  const unsigned short* Asrc0 = A + (size_t)(bm + (c0 << 4) + srow) * astr + scol;
  const unsigned short* Asrc1 = Asrc0 + (size_t)16 * astr;
  const unsigned short* Bsrc0 = Bp + (size_t)(bnw + (c0 << 4) + srow) * HIDC + scol;
  const unsigned short* Bsrc1 = Bsrc0 + (size_t)16 * HIDC;
  const int adst = c0 << 9;               // ushort idx within op region

  // fragment read offsets (swizzled): row*32 + ((l4 ^ ((row>>1)&3))<<3)
  const int xa = ((l4 ^ ((l15 >> 1) & 3)) << 3);
  const int abase = ((wr << 7) + l15) * 32 + xa;
  const int bbase = 8192 + ((wc << 6) + l15) * 32 + xa;

  f32x4 acc[8][4] = {};
  s16x8 af[2][8];    // A frags, double-buffered across steps (parity = step&1)
  s16x8 bfr[4];      // B frags, same-step single set

#define STAGE_A(s_) { const int sl_ = ((s_) & 3) << 14; const int kt_ = (s_) << 5; \
    gload_lds16(Asrc0 + kt_, &lds[sl_ + adst]); \
    gload_lds16(Asrc1 + kt_, &lds[sl_ + adst + 512]); }
#define STAGE_B(s_) { const int sl_ = ((s_) & 3) << 14; const int kt_ = (s_) << 5; \
    gload_lds16(Bsrc0 + kt_, &lds[sl_ + 8192 + adst]); \
    gload_lds16(Bsrc1 + kt_, &lds[sl_ + 8192 + adst + 512]); }

#define MM8(nf_, P_) { \
    acc[0][nf_] = __builtin_amdgcn_mfma_f32_16x16x32_bf16(af[P_][0], bfr[nf_], acc[0][nf_], 0, 0, 0); \
    acc[1][nf_] = __builtin_amdgcn_mfma_f32_16x16x32_bf16(af[P_][1], bfr[nf_], acc[1][nf_], 0, 0, 0); \
    acc[2][nf_] = __builtin_amdgcn_mfma_f32_16x16x32_bf16(af[P_][2], bfr[nf_], acc[2][nf_], 0, 0, 0); \
    acc[3][nf_] = __builtin_amdgcn_mfma_f32_16x16x32_bf16(af[P_][3], bfr[nf_], acc[3][nf_], 0, 0, 0); \
    acc[4][nf_] = __builtin_amdgcn_mfma_f32_16x16x32_bf16(af[P_][4], bfr[nf_], acc[4][nf_], 0, 0, 0); \
    acc[5][nf_] = __builtin_amdgcn_mfma_f32_16x16x32_bf16(af[P_][5], bfr[nf_], acc[5][nf_], 0, 0, 0); \
    acc[6][nf_] = __builtin_amdgcn_mfma_f32_16x16x32_bf16(af[P_][6], bfr[nf_], acc[6][nf_], 0, 0, 0); \
    acc[7][nf_] = __builtin_amdgcn_mfma_f32_16x16x32_bf16(af[P_][7], bfr[nf_], acc[7][nf_], 0, 0, 0); }

#define DO_STEP(s_, P_, GATE, DO_A, DO_STG) { \
    const int sl = ((s_) & 3) << 14; \
    if ((GATE) == 4)      { asm volatile("s_waitcnt vmcnt(4)" ::: "memory"); } \
    else if ((GATE) == 0) { asm volatile("s_waitcnt vmcnt(0)" ::: "memory"); } \
    __builtin_amdgcn_s_barrier(); \
    bfr[0] = *(const s16x8*)&lds[sl + bbase]; \
    bfr[1] = *(const s16x8*)&lds[sl + bbase + 512]; \
    bfr[2] = *(const s16x8*)&lds[sl + bbase + 1024]; \
    bfr[3] = *(const s16x8*)&lds[sl + bbase + 1536]; \
    if (DO_A) { \
      const int sln = (((s_) + 1) & 3) << 14; \
      af[1-(P_)][0] = *(const s16x8*)&lds[sln + abase]; \
      af[1-(P_)][1] = *(const s16x8*)&lds[sln + abase + 512]; \
      af[1-(P_)][2] = *(const s16x8*)&lds[sln + abase + 1024]; \
      af[1-(P_)][3] = *(const s16x8*)&lds[sln + abase + 1536]; \
      af[1-(P_)][4] = *(const s16x8*)&lds[sln + abase + 2048]; \
      af[1-(P_)][5] = *(const s16x8*)&lds[sln + abase + 2560]; \
      af[1-(P_)][6] = *(const s16x8*)&lds[sln + abase + 3072]; \
      af[1-(P_)][7] = *(const s16x8*)&lds[sln + abase + 3584]; \
    } \
    if (DO_STG) { STAGE_A((s_) + 3); STAGE_B((s_) + 3); } \
    __builtin_amdgcn_sched_barrier(0); \
    __builtin_amdgcn_s_setprio(1); \
    MM8(0, P_) MM8(1, P_) MM8(2, P_) MM8(3, P_) \
    __builtin_amdgcn_s_setprio(0); \
  }

  // prologue: stage slots 0,1,2 (12 loads/wave); slot 0 resident; pre-read a(0)
  STAGE_A(0); STAGE_B(0);
  STAGE_A(1); STAGE_B(1);
  STAGE_A(2); STAGE_B(2);
  asm volatile("s_waitcnt vmcnt(8)" ::: "memory");
  __builtin_amdgcn_s_barrier();
  af[0][0] = *(const s16x8*)&lds[abase];
  af[0][1] = *(const s16x8*)&lds[abase + 512];
  af[0][2] = *(const s16x8*)&lds[abase + 1024];
  af[0][3] = *(const s16x8*)&lds[abase + 1536];
  af[0][4] = *(const s16x8*)&lds[abase + 2048];
  af[0][5] = *(const s16x8*)&lds[abase + 2560];
  af[0][6] = *(const s16x8*)&lds[abase + 3072];
  af[0][7] = *(const s16x8*)&lds[abase + 3584];

  for (int s = 0; s < 60; s += 2) {
    DO_STEP(s,     0, 4, 1, 1)
    DO_STEP(s + 1, 1, 4, 1, 1)
  }
  DO_STEP(60, 0, 4, 1, 1)   // stages slot 63
  DO_STEP(61, 1, 4, 1, 0)
  DO_STEP(62, 0, 0, 1, 0)
  DO_STEP(63, 1, -1, 0, 0)

#undef DO_STEP
#undef MM8
#undef STAGE_A
#undef STAGE_B

  #pragma unroll
  for (int nf = 0; nf < 4; ++nf) {
    const int colw = (wc << 6) + (nf << 4) + l15;
    const float bv = bias[bnw + colw];
    #pragma unroll
    for (int mf = 0; mf < 8; ++mf) {
      #pragma unroll
      for (int r = 0; r < 4; ++r) {
        const int row = bm + (wr << 7) + (mf << 4) + (l4 << 2) + r;
        float v = acc[mf][nf][r] + bv;
        if (QKV) { if (act) v = (v > 0.f) ? (v + 1.f) : __expf(v); }
        const size_t off = (size_t)row * ostr + bn + colw;
        if (OUT_BF16) ((unsigned short*)Cp)[off] = f2b(v);
        else          ((float*)Cp)[off] = v;
      }
    }
  }
}

// kv partials over 16 S-chunks (deterministic, no atomics). 1024 blocks -> 4/CU.
__global__ __launch_bounds__(256) void kv_partial(
    const unsigned short* __restrict__ kp, const unsigned short* __restrict__ vv,
    float* __restrict__ kvp, float* __restrict__ ksp)
{
  const int bh = blockIdx.x >> 4;
  const int chunk = blockIdx.x & 15;
  const int b = bh >> 4, h = bh & 15;
  const int tid = threadIdx.x;
  const int td = tid >> 4, te = tid & 15;

  __shared__ float kpl[32][128];
  __shared__ float vl[32][132];

  float acc[8][8] = {};
  float ks[8] = {};

  const size_t rowbase = (size_t)b * NS * QSTR + (size_t)h * HDIM;
  const int s0 = chunk * 256;

  for (int st = 0; st < 256; st += 32) {
    __syncthreads();
    #pragma unroll
    for (int i = 0; i < 2; ++i) {
      int idx = tid + (i << 8);
      int row = idx >> 4, q = idx & 15;
      size_t g = rowbase + (size_t)(s0 + st + row) * QSTR + (q << 3);
      u16x8 k8 = *(const u16x8*)(kp + g);
      u16x8 v8 = *(const u16x8*)(vv + g);
      float tk[8], tv[8];
      #pragma unroll
      for (int j = 0; j < 8; ++j) { tk[j] = b2f(k8[j]); tv[j] = b2f(v8[j]); }
      *(float4*)&kpl[row][(q << 3)]     = make_float4(tk[0], tk[1], tk[2], tk[3]);
      *(float4*)&kpl[row][(q << 3) + 4] = make_float4(tk[4], tk[5], tk[6], tk[7]);
      *(float4*)&vl[row][(q << 3)]      = make_float4(tv[0], tv[1], tv[2], tv[3]);
      *(float4*)&vl[row][(q << 3) + 4]  = make_float4(tv[4], tv[5], tv[6], tv[7]);
    }
    __syncthreads();
    #pragma unroll 4
    for (int s = 0; s < 32; ++s) {
      float kd[8], ve[8];
      *(float4*)&kd[0] = *(const float4*)&kpl[s][td << 3];
      *(float4*)&kd[4] = *(const float4*)&kpl[s][(td << 3) + 4];
      *(float4*)&ve[0] = *(const float4*)&vl[s][te << 3];
      *(float4*)&ve[4] = *(const float4*)&vl[s][(te << 3) + 4];
      if (te == 0) {
        #pragma unroll
        for (int i = 0; i < 8; ++i) ks[i] += kd[i];
      }
      #pragma unroll
      for (int i = 0; i < 8; ++i)
        #pragma unroll
        for (int j = 0; j < 8; ++j)
          acc[i][j] += kd[i] * ve[j];
    }
  }

  float* outp = kvp + ((size_t)(chunk * 64 + bh) << 14);
  #pragma unroll
  for (int j = 0; j < 8; ++j) {
    int e = (te << 3) + j;
    float r0[8];
    #pragma unroll
    for (int i = 0; i < 8; ++i) r0[i] = acc[i][j];
    *(float4*)&outp[(size_t)e * HDIM + (td << 3)]     = *(float4*)&r0[0];
    *(float4*)&outp[(size_t)e * HDIM + (td << 3) + 4] = *(float4*)&r0[4];
  }
  if (te == 0) {
    float* kso = ksp + ((size_t)(chunk * 64 + bh) << 7) + (td << 3);
    #pragma unroll
    for (int i = 0; i < 8; ++i) kso[i] = ks[i];
  }
}

__global__ __launch_bounds__(256) void kv_reduce(
    const float* __restrict__ kvp, float* __restrict__ kvT)
{
  int i = blockIdx.x * 256 + threadIdx.x;
  float s = 0.f;
  #pragma unroll
  for (int c = 0; c < 16; ++c) s += kvp[(size_t)c * (64 * 16384) + i];
  kvT[i] = s;
}

// attn[s,e] = (qp[s,:] . kvT[e,:]) / (z[s]+eps); qp = q cols of qkv, out -> v cols.
__global__ __launch_bounds__(256) void attn_ker(
    const unsigned short* __restrict__ qp, const float* __restrict__ kvT,
    const float* __restrict__ ksp, unsigned short* __restrict__ attn)
{
  const int bh = blockIdx.x >> 5, stile = blockIdx.x & 31;
  const int b = bh >> 4, h = bh & 15;
  const int tid = threadIdx.x;
  const int lane = tid & 63, w = tid >> 6;
  const int l15 = lane & 15, l4 = lane >> 4;

  __shared__ unsigned short Qs[128][136];
  __shared__ unsigned short Ks[128][136];
  __shared__ float ksl[128];
  __shared__ float zs[128];

  const size_t qbase = ((size_t)b * NS + (size_t)stile * 128) * QSTR + (size_t)h * HDIM;

  #pragma unroll
  for (int i = 0; i < 8; ++i) {
    int idx = tid + (i << 8);
    int row = idx >> 4, q = idx & 15;
    u16x8 v8 = *(const u16x8*)(qp + qbase + (size_t)row * QSTR + (q << 3));
    *(u16x8*)&Qs[row][q << 3] = v8;
  }
  const float* kvb = kvT + ((size_t)bh << 14);
  #pragma unroll
  for (int i = 0; i < 16; ++i) {
    int idx = tid + (i << 8);
    int row = idx >> 5, q = idx & 31;
    float4 v4 = *(const float4*)(kvb + (size_t)row * HDIM + (q << 2));
    ushort4 w4; w4.x = f2b(v4.x); w4.y = f2b(v4.y); w4.z = f2b(v4.z); w4.w = f2b(v4.w);
    *(ushort4*)&Ks[row][q << 2] = w4;
  }
  if (tid < 128) {
    float s = 0.f;
    #pragma unroll
    for (int c = 0; c < 16; ++c) s += ksp[((size_t)(c * 64 + bh) << 7) + tid];
    ksl[tid] = s;
  }
  __syncthreads();
  if (tid < 128) {
    float z = 0.f;
    #pragma unroll
    for (int dq = 0; dq < 16; ++dq) {
      u16x8 qv = *(const u16x8*)&Qs[tid][dq << 3];
      #pragma unroll
      for (int j = 0; j < 8; ++j) z += b2f(qv[j]) * ksl[(dq << 3) + j];
    }
    zs[tid] = 1.f / (z + EPSV);
  }
  __syncthreads();

  f32x4 acc[2][8] = {};
  #pragma unroll
  for (int kk = 0; kk < 4; ++kk) {
    s16x8 a[2], bb[8];
    #pragma unroll
    for (int mf = 0; mf < 2; ++mf)
      a[mf] = *(const s16x8*)&Qs[(w << 5) + (mf << 4) + l15][(kk << 5) + (l4 << 3)];
    #pragma unroll
    for (int nf = 0; nf < 8; ++nf)
      bb[nf] = *(const s16x8*)&Ks[(nf << 4) + l15][(kk << 5) + (l4 << 3)];
    #pragma unroll
    for (int mf = 0; mf < 2; ++mf)
      #pragma unroll
      for (int nf = 0; nf < 8; ++nf)
        acc[mf][nf] = __builtin_amdgcn_mfma_f32_16x16x32_bf16(a[mf], bb[nf], acc[mf][nf], 0, 0, 0);
  }

  #pragma unroll
  for (int mf = 0; mf < 2; ++mf) {
    #pragma unroll
    for (int r = 0; r < 4; ++r) {
      const int rl = (w << 5) + (mf << 4) + (l4 << 2) + r;
      const float zi = zs[rl];
      #pragma unroll
      for (int nf = 0; nf < 8; ++nf) {
        const int e = (nf << 4) + l15;
        attn[qbase + (size_t)rl * QSTR + e] = f2b(acc[mf][nf][r] * zi);
      }
    }
  }
}

extern "C" void kernel_launch(void* const* d_in, const int* in_sizes, int n_in,
                              void* d_out, int out_size, void* d_ws, size_t ws_size,
                              hipStream_t stream) {
  const float* hs = (const float*)d_in[0];
  const float* qw = (const float*)d_in[1];
  const float* qb = (const float*)d_in[2];
  const float* kw = (const float*)d_in[3];
  const float* kb = (const float*)d_in[4];
  const float* vw = (const float*)d_in[5];
  const float* vb = (const float*)d_in[6];
  const float* ow = (const float*)d_in[7];
  const float* ob = (const float*)d_in[8];

  char* w = (char*)d_ws;
  unsigned short* hsb = (unsigned short*)(w);                  // 64 MiB (dead after QKV gemm)
  unsigned short* qwb = (unsigned short*)(w + 67108864);       // 8 MiB each (q/k/v dead after QKV)
  unsigned short* kwb = (unsigned short*)(w + 75497472);
  unsigned short* vwb = (unsigned short*)(w + 83886080);
  unsigned short* owb = (unsigned short*)(w + 92274688);
  unsigned short* qkv = (unsigned short*)(w + 100663296);      // 192 MiB, row stride 6144
  // aliases over dead regions after QKV:
  float* kvp = (float*)(w);                                    // 64 MiB (16 chunks) over hsb
  float* ksp = (float*)(w + 67108864);                         // 512 KiB over qwb
  float* kvT = (float*)(w + 67108864 + 524288);                // 4 MiB over qwb

  convert_all<<<dim3(24576), dim3(256), 0, stream>>>(hs, qw, kw, vw, ow, hsb, qwb, kwb, vwb, owb);
  // QKV fused: M=16384, N=6144 (q|k|v columns), elu+1 on q,k
  gemm256<1, 1><<<dim3(24 * 64), dim3(512), 0, stream>>>(
      hsb, qwb, kwb, vwb, qb, kb, vb, qkv, 24, HIDC, QSTR);
  kv_partial<<<dim3(1024), dim3(256), 0, stream>>>(qkv + 2048, qkv + 4096, kvp, ksp);
  kv_reduce<<<dim3(4096), dim3(256), 0, stream>>>(kvp, kvT);
  attn_ker<<<dim3(2048), dim3(256), 0, stream>>>(qkv, kvT, ksp, qkv + 4096);
  // final: out = attn @ o_w^T + o_b, A = v-columns of qkv (astr=QSTR), fp32 out
  gemm256<0, 0><<<dim3(8 * 64), dim3(512), 0, stream>>>(
      qkv + 4096, owb, owb, owb, ob, ob, ob, d_out, 8, QSTR, HIDC);
}